// Round 8
// baseline (590.639 us; speedup 1.0000x reference)
//
#include <hip/hip_runtime.h>
#include <hip/hip_bf16.h>
#include <cstdint>
#include <cstddef>

// Problem constants
#define NMEM 16
#define DDIM 512
#define BATCH 4
#define LSEQ 4096
#define ROWS 16384      // BATCH*LSEQ
#define NCAND 32        // fp8-noise safety: rank-8..32 gap ~4.5+ sigma
#define KTOP 8
#define QPAD 20

typedef __attribute__((ext_vector_type(4))) float f32x4;
typedef __attribute__((ext_vector_type(16))) float f32x16;
typedef __attribute__((ext_vector_type(8))) int int8v;

__device__ inline void gld16(const void* gptr, void* lptr) {
    __builtin_amdgcn_global_load_lds(
        (const __attribute__((address_space(1))) unsigned int*)gptr,
        (__attribute__((address_space(3))) unsigned int*)lptr,
        16, 0, 0);
}

__device__ inline float fast_tanh(float p) {
    p = fminf(fmaxf(p, -15.f), 15.f);
    float e = __expf(2.f * p);
    return (e - 1.f) / (e + 1.f);
}

// MX frag from a 128-B-row tile: chunks 2g^h, (2g+1)^h of row (h = row&7 swizzle)
__device__ inline int8v load_frag(const unsigned char* Ts, int row, int g) {
    int h = row & 7;
    const int4* p0 = (const int4*)(Ts + row * 128 + (((2 * g) ^ h) << 4));
    const int4* p1 = (const int4*)(Ts + row * 128 + (((2 * g + 1) ^ h) << 4));
    int4 x = *p0, y = *p1;
    int8v v;
    v[0] = x.x; v[1] = x.y; v[2] = x.z; v[3] = x.w;
    v[4] = y.x; v[5] = y.y; v[6] = y.z; v[7] = y.w;
    return v;
}

__device__ inline int8v pack8(int4 x, int4 y) {
    int8v v;
    v[0] = x.x; v[1] = x.y; v[2] = x.z; v[3] = x.w;
    v[4] = y.x; v[5] = y.y; v[6] = y.z; v[7] = y.w;
    return v;
}

// ---------- fused prep: Q->fp8, W1/W2 transpose->fp8, zero logits ----------
__global__ __launch_bounds__(256)
void prep_kernel(const float* __restrict__ query,
                 const float* __restrict__ W1, const float* __restrict__ W2,
                 unsigned char* __restrict__ Q8,
                 unsigned char* __restrict__ W1T8, unsigned char* __restrict__ W2T8,
                 float* __restrict__ logits) {
    int blk = blockIdx.x, t = threadIdx.x;
    if (blk < 2048) {                       // Q convert: 16 els/thread
        size_t base = ((size_t)blk * 256 + t) * 16;
        const float4* in = (const float4*)(query + base);
        int4 o; int* op = (int*)&o;
        #pragma unroll
        for (int q = 0; q < 4; ++q) {
            float4 v = in[q];
            int lo = __builtin_amdgcn_cvt_pk_fp8_f32(v.x, v.y, 0, false);
            op[q] = __builtin_amdgcn_cvt_pk_fp8_f32(v.z, v.w, lo, true);
        }
        *(int4*)(Q8 + base) = o;
    } else if (blk < 4096) {                // W transpose+convert, 64x64 tiles
        __shared__ float tile[64][69];
        int bid = blk - 2048;
        const float* Win = W1; unsigned char* Wout = W1T8;
        if (bid >= 1024) { bid -= 1024; Win = W2; Wout = W2T8; }
        int n = bid >> 6, t64 = bid & 63;
        int dt = (t64 >> 3) << 6, jt = (t64 & 7) << 6;
        const float* inN = Win + (size_t)n * DDIM * DDIM;
        unsigned char* outN = Wout + (size_t)n * DDIM * DDIM;
        int rr = t >> 4, cc = (t & 15) * 4;
        #pragma unroll
        for (int pass = 0; pass < 4; ++pass) {
            int row = rr + pass * 16;
            float4 v = *(const float4*)(inN + (size_t)(dt + row) * DDIM + jt + cc);
            tile[row][cc] = v.x; tile[row][cc + 1] = v.y;
            tile[row][cc + 2] = v.z; tile[row][cc + 3] = v.w;
        }
        __syncthreads();
        #pragma unroll
        for (int pass = 0; pass < 4; ++pass) {
            int jl = rr + pass * 16;
            float f0 = tile[cc][jl], f1 = tile[cc + 1][jl];
            float f2 = tile[cc + 2][jl], f3 = tile[cc + 3][jl];
            int lo = __builtin_amdgcn_cvt_pk_fp8_f32(f0, f1, 0, false);
            int dw = __builtin_amdgcn_cvt_pk_fp8_f32(f2, f3, lo, true);
            *(int*)(outN + (size_t)(jt + jl) * DDIM + dt + cc) = dw;
        }
    } else {                                // zero logits (1 MB)
        int bid = blk - 4096;
        ((int4*)logits)[bid * 256 + t] = int4{0, 0, 0, 0};
    }
}

// ---------- fused MLP (v4): operand-swapped, double-buffered, raw-barrier pipeline ----
// grid 4096 = 256 m-tiles x 16 slots. Block 256 = 4 waves (rh,ch); M=64 rows.
// A = W-tile (LDS, dbuf), B = Q/h (global regs / LDS). C: col=lane&31 = q-row,
// reg -> j = base + 4*kh + 8*(reg>>2) + (reg&3). LDS 64 KB -> 2 blocks/CU.
__global__ __launch_bounds__(256, 2)
void fused_mlp_kernel(const unsigned char* __restrict__ Q8,
                      const unsigned char* __restrict__ W1T8,
                      const unsigned char* __restrict__ W2T8,
                      const float* __restrict__ b1, const float* __restrict__ b2,
                      const float* __restrict__ Wg,
                      float* __restrict__ logits)
{
    __shared__ unsigned char hbuf[64 * 512];   // 32 KB fp8 h, chunk^(row&7) swizzle
    __shared__ unsigned char Bs[2][128 * 128]; // 2 x 16 KB W-tile (double buffer)
    const int id = blockIdx.x;
    const int n = id & 15;
    const int m0 = (id >> 4) * 64;
    const int tid = threadIdx.x, lane = tid & 63, w = tid >> 6;
    const int rh = w >> 1, ch = w & 1;
    const int l31 = lane & 31, kh = lane >> 5;
    const unsigned char* W1n = W1T8 + (size_t)n * DDIM * DDIM;
    const unsigned char* W2n = W2T8 + (size_t)n * DDIM * DDIM;
    const float slope = 0.01f + 0.0125f * n;
    const int hrow = rh * 32 + l31, hq = hrow & 7;
    const unsigned char* Aq0 = Q8 + (size_t)(m0 + hrow) * DDIM + kh * 32;

    // stage tile for flat stage index s (n0 = s>>2, kt = s&3) into Bs[buf]
    auto stageW = [&](const unsigned char* Wn, int s, int buf) {
        int n0 = s >> 2, kt = s & 3;
        const unsigned char* Bg = Wn + (size_t)(n0 * 128) * DDIM + kt * 128;
        #pragma unroll
        for (int i = 0; i < 4; ++i) {
            int c = i * 256 + tid;
            int row = c >> 3, chk = c & 7;
            gld16(Bg + (size_t)row * DDIM + ((chk ^ (row & 7)) << 4), &Bs[buf][c * 16]);
        }
    };

    // ---- Phase A: h = leaky(Q W1 + b1) -> hbuf ----
    f32x16 accA[2];
    stageW(W1n, 0, 0);
    for (int s = 0; s < 16; ++s) {
        int n0 = s >> 2, kt = s & 3;
        if (kt == 0) {
            #pragma unroll
            for (int fc = 0; fc < 2; ++fc)
                #pragma unroll
                for (int i = 0; i < 16; ++i) accA[fc][i] = 0.f;
        }
        // Q B-frags for this stage (global, 4 vmem)
        int8v qf[2];
        #pragma unroll
        for (int ks = 0; ks < 2; ++ks) {
            const unsigned char* ap = Aq0 + kt * 128 + ks * 64;
            qf[ks] = pack8(*(const int4*)ap, *(const int4*)(ap + 16));
        }
        if (s < 15) stageW(W1n, s + 1, (s + 1) & 1);
        asm volatile("s_waitcnt vmcnt(8)\ns_barrier" ::: "memory");
        const unsigned char* Bcur = Bs[s & 1];
        #pragma unroll
        for (int ks = 0; ks < 2; ++ks)
            #pragma unroll
            for (int fc = 0; fc < 2; ++fc) {
                int8v wf = load_frag(Bcur, ch * 64 + fc * 32 + l31, ks * 2 + kh);
                accA[fc] = __builtin_amdgcn_mfma_scale_f32_32x32x64_f8f6f4(
                    wf, qf[ks], accA[fc], 0, 0, 0, 0x7F7F7F7F, 0, 0x7F7F7F7F);
            }
        asm volatile("s_waitcnt lgkmcnt(0)\ns_barrier" ::: "memory");
        if (kt == 3) {
            // epilogue: bias + leaky, pack 4 j-bytes per dword into swizzled hbuf
            #pragma unroll
            for (int fc = 0; fc < 2; ++fc)
                #pragma unroll
                for (int g2 = 0; g2 < 4; ++g2) {
                    int j0 = n0 * 128 + ch * 64 + fc * 32 + 4 * kh + 8 * g2;
                    float4 bb = *(const float4*)&b1[n * DDIM + j0];
                    float v0 = accA[fc][g2 * 4 + 0] + bb.x; v0 = v0 >= 0.f ? v0 : v0 * slope;
                    float v1 = accA[fc][g2 * 4 + 1] + bb.y; v1 = v1 >= 0.f ? v1 : v1 * slope;
                    float v2 = accA[fc][g2 * 4 + 2] + bb.z; v2 = v2 >= 0.f ? v2 : v2 * slope;
                    float v3 = accA[fc][g2 * 4 + 3] + bb.w; v3 = v3 >= 0.f ? v3 : v3 * slope;
                    int lo = __builtin_amdgcn_cvt_pk_fp8_f32(v0, v1, 0, false);
                    int dw = __builtin_amdgcn_cvt_pk_fp8_f32(v2, v3, lo, true);
                    *(int*)&hbuf[hrow * 512 + (((j0 >> 4) ^ hq) << 4) + (j0 & 15)] = dw;
                }
        }
    }
    __syncthreads();   // hbuf complete; full drain once at phase boundary

    // ---- Phase B: rowsum = sum_j tanh(h W2 + b2)[row][j] * Wg[j] ----
    float rowpart = 0.f;
    f32x16 accB[2];
    stageW(W2n, 0, 0);
    for (int s = 0; s < 16; ++s) {
        int n0 = s >> 2, kt = s & 3;
        if (kt == 0) {
            #pragma unroll
            for (int fc = 0; fc < 2; ++fc)
                #pragma unroll
                for (int i = 0; i < 16; ++i) accB[fc][i] = 0.f;
        }
        if (s < 15) stageW(W2n, s + 1, (s + 1) & 1);
        asm volatile("s_waitcnt vmcnt(4)\ns_barrier" ::: "memory");
        const unsigned char* Bcur = Bs[s & 1];
        #pragma unroll
        for (int ks = 0; ks < 2; ++ks) {
            // h B-frag: lane&31 = q-row, k bytes kt*128 + ks*64 + kh*32
            int C0 = kt * 8 + ks * 4 + 2 * kh;
            const int4* p0 = (const int4*)(hbuf + hrow * 512 + ((C0 ^ hq) << 4));
            const int4* p1 = (const int4*)(hbuf + hrow * 512 + (((C0 + 1) ^ hq) << 4));
            int8v hf = pack8(*p0, *p1);
            #pragma unroll
            for (int fc = 0; fc < 2; ++fc) {
                int8v wf = load_frag(Bcur, ch * 64 + fc * 32 + l31, ks * 2 + kh);
                accB[fc] = __builtin_amdgcn_mfma_scale_f32_32x32x64_f8f6f4(
                    wf, hf, accB[fc], 0, 0, 0, 0x7F7F7F7F, 0, 0x7F7F7F7F);
            }
        }
        asm volatile("s_waitcnt lgkmcnt(0)\ns_barrier" ::: "memory");
        if (kt == 3) {
            #pragma unroll
            for (int fc = 0; fc < 2; ++fc)
                #pragma unroll
                for (int g2 = 0; g2 < 4; ++g2) {
                    int j0 = n0 * 128 + ch * 64 + fc * 32 + 4 * kh + 8 * g2;
                    float4 bb = *(const float4*)&b2[n * DDIM + j0];
                    float4 wg4 = *(const float4*)&Wg[n * DDIM + j0];
                    rowpart = fmaf(fast_tanh(accB[fc][g2 * 4 + 0] + bb.x), wg4.x, rowpart);
                    rowpart = fmaf(fast_tanh(accB[fc][g2 * 4 + 1] + bb.y), wg4.y, rowpart);
                    rowpart = fmaf(fast_tanh(accB[fc][g2 * 4 + 2] + bb.z), wg4.z, rowpart);
                    rowpart = fmaf(fast_tanh(accB[fc][g2 * 4 + 3] + bb.w), wg4.w, rowpart);
                }
        }
    }
    rowpart += __shfl_xor(rowpart, 32);   // merge kh halves (same q-row)
    if (kh == 0)
        atomicAdd(&logits[(size_t)n * ROWS + m0 + hrow], rowpart);
}

// ---------- topcand: per (n,b) top-32 of 4096 ----------
__global__ __launch_bounds__(256)
void topcand_kernel(const float* __restrict__ logits, int* __restrict__ cand,
                    float* __restrict__ ex_logit) {
    __shared__ float lv[LSEQ];
    __shared__ float cv[128];
    __shared__ int   ci[128];
    int p = blockIdx.x, n = p >> 2, b = p & 3;
    int t = threadIdx.x, lane = t & 63, w = t >> 6;
    const float* L = logits + (size_t)n * ROWS + (size_t)b * LSEQ;
    for (int i = t; i < LSEQ; i += 256) lv[i] = L[i];
    __syncthreads();
    float mv[16];
    int base = w * 1024;
    #pragma unroll
    for (int j = 0; j < 16; ++j) mv[j] = lv[base + j * 64 + lane];
    for (int rd = 0; rd < 32; ++rd) {
        float best = mv[0]; int bj = 0;
        #pragma unroll
        for (int j = 1; j < 16; ++j)
            if (mv[j] > best) { best = mv[j]; bj = j; }
        int bidx = base + bj * 64 + lane;
        float rv = best; int ridx = bidx;
        #pragma unroll
        for (int s = 1; s < 64; s <<= 1) {
            float ov = __shfl_xor(rv, s); int oi = __shfl_xor(ridx, s);
            if (ov > rv || (ov == rv && oi < ridx)) { rv = ov; ridx = oi; }
        }
        if (lane == 0) { cv[w * 32 + rd] = rv; ci[w * 32 + rd] = ridx; }
        if (ridx == bidx) mv[bj] = -1e30f;
    }
    __syncthreads();
    if (w == 0) {
        float v2[2]; int i2[2];
        #pragma unroll
        for (int k = 0; k < 2; ++k) { v2[k] = cv[k * 64 + lane]; i2[k] = ci[k * 64 + lane]; }
        for (int rd = 0; rd < 32; ++rd) {
            float best = v2[0]; int bi = i2[0]; int bk = 0;
            if (v2[1] > best || (v2[1] == best && i2[1] < bi)) { best = v2[1]; bi = i2[1]; bk = 1; }
            float rv = best; int ridx = bi;
            #pragma unroll
            for (int s = 1; s < 64; s <<= 1) {
                float ov = __shfl_xor(rv, s); int oi = __shfl_xor(ridx, s);
                if (ov > rv || (ov == rv && oi < ridx)) { rv = ov; ridx = oi; }
            }
            if (lane == 0) cand[p * NCAND + rd] = ridx;
            if (ridx == bi) v2[bk] = -1e30f;
        }
    } else if (w == 1) {
        if (lane < NCAND) ex_logit[p * NCAND + lane] = 0.f;
    }
}

// ---------- exact fp32 recompute: phase 1 (h) ----------
__global__ __launch_bounds__(256)
void exact_h_kernel(const float* __restrict__ query,
                    const float* __restrict__ W1, const float* __restrict__ b1,
                    const int* __restrict__ cand, float* __restrict__ ex_h) {
    __shared__ float qs[DDIM][QPAD];
    __shared__ float hpart[4][16][64];
    int blk = blockIdx.x;
    int p = blk >> 4, r4 = blk & 15;
    int ct = r4 >> 3, jc = r4 & 7;
    int n = p >> 2, b = p & 3;
    int t = threadIdx.x, jj = t & 63, dg = t >> 6;
    int j = jc * 64 + jj;
    for (int c = 0; c < 16; ++c) {
        int li = cand[p * NCAND + ct * 16 + c];
        const float* qr = query + ((size_t)b * LSEQ + li) * DDIM;
        for (int d = t; d < DDIM; d += 256) qs[d][c] = qr[d];
    }
    __syncthreads();
    const float* W1n = W1 + (size_t)n * DDIM * DDIM;
    float acc[16] = {};
    for (int d = dg * 128; d < dg * 128 + 128; ++d) {
        float wvv = W1n[(size_t)d * DDIM + j];
        const float4* qv = (const float4*)&qs[d][0];
        #pragma unroll
        for (int c4 = 0; c4 < 4; ++c4) {
            float4 q4 = qv[c4];
            acc[c4 * 4 + 0] = fmaf(q4.x, wvv, acc[c4 * 4 + 0]);
            acc[c4 * 4 + 1] = fmaf(q4.y, wvv, acc[c4 * 4 + 1]);
            acc[c4 * 4 + 2] = fmaf(q4.z, wvv, acc[c4 * 4 + 2]);
            acc[c4 * 4 + 3] = fmaf(q4.w, wvv, acc[c4 * 4 + 3]);
        }
    }
    #pragma unroll
    for (int c = 0; c < 16; ++c) hpart[dg][c][jj] = acc[c];
    __syncthreads();
    const float slope = 0.01f + 0.0125f * n;
    float bias = b1[n * DDIM + j];
    for (int cc = dg; cc < 16; cc += 4) {
        float h = hpart[0][cc][jj] + hpart[1][cc][jj] + hpart[2][cc][jj]
                + hpart[3][cc][jj] + bias;
        h = h >= 0.f ? h : h * slope;
        ex_h[((size_t)p * NCAND + ct * 16 + cc) * DDIM + j] = h;
    }
}

// ---------- exact phase 2: x + exact logits ----------
__global__ __launch_bounds__(256)
void exact_x_kernel(const float* __restrict__ ex_h,
                    const float* __restrict__ W2, const float* __restrict__ b2,
                    const float* __restrict__ Wg,
                    float* __restrict__ ex_x, float* __restrict__ ex_logit) {
    __shared__ float hs[DDIM][QPAD];
    __shared__ float xpart[4][16][64];
    int blk = blockIdx.x;
    int p = blk >> 4, r4 = blk & 15;
    int ct = r4 >> 3, jc = r4 & 7;
    int n = p >> 2;
    int t = threadIdx.x, jj = t & 63, dg = t >> 6;
    int j = jc * 64 + jj;
    for (int c = 0; c < 16; ++c) {
        const float* hr = ex_h + ((size_t)p * NCAND + ct * 16 + c) * DDIM;
        for (int d = t; d < DDIM; d += 256) hs[d][c] = hr[d];
    }
    __syncthreads();
    const float* W2n = W2 + (size_t)n * DDIM * DDIM;
    float acc[16] = {};
    for (int d = dg * 128; d < dg * 128 + 128; ++d) {
        float wvv = W2n[(size_t)d * DDIM + j];
        const float4* hv = (const float4*)&hs[d][0];
        #pragma unroll
        for (int c4 = 0; c4 < 4; ++c4) {
            float4 h4 = hv[c4];
            acc[c4 * 4 + 0] = fmaf(h4.x, wvv, acc[c4 * 4 + 0]);
            acc[c4 * 4 + 1] = fmaf(h4.y, wvv, acc[c4 * 4 + 1]);
            acc[c4 * 4 + 2] = fmaf(h4.z, wvv, acc[c4 * 4 + 2]);
            acc[c4 * 4 + 3] = fmaf(h4.w, wvv, acc[c4 * 4 + 3]);
        }
    }
    #pragma unroll
    for (int c = 0; c < 16; ++c) xpart[dg][c][jj] = acc[c];
    __syncthreads();
    float bias = b2[n * DDIM + j];
    float wg = Wg[n * DDIM + j];
    for (int cc = dg; cc < 16; cc += 4) {
        float a = xpart[0][cc][jj] + xpart[1][cc][jj] + xpart[2][cc][jj]
                + xpart[3][cc][jj] + bias;
        float x = tanhf(a);
        ex_x[((size_t)p * NCAND + ct * 16 + cc) * DDIM + j] = x;
        float lp = x * wg;
        #pragma unroll
        for (int s = 1; s < 64; s <<= 1) lp += __shfl_xor(lp, s);
        if (jj == 0) atomicAdd(&ex_logit[p * NCAND + ct * 16 + cc], lp);
    }
}

// ---------- final: exact top-8 of 32, weight, combine, normalize ----------
__global__ __launch_bounds__(64)
void final_kernel(const float* __restrict__ ex_x, const float* __restrict__ ex_logit,
                  const int* __restrict__ cand, float* __restrict__ out)
{
    __shared__ float w8s[KTOP];
    __shared__ int   s8s[KTOP];
    int p = blockIdx.x, n = p >> 2, b = p & 3;
    int t = threadIdx.x;
    float myv = (t < NCAND) ? ex_logit[p * NCAND + t] : -1e30f;
    int myidx = (t < NCAND) ? cand[p * NCAND + t] : 0x7fffffff;
    float lmax = 0.f;
    for (int k = 0; k < KTOP; ++k) {
        float rv = myv; int ridx = myidx; int rl = t;
        #pragma unroll
        for (int s = 1; s < 64; s <<= 1) {
            float ov = __shfl_xor(rv, s); int oi = __shfl_xor(ridx, s); int ol = __shfl_xor(rl, s);
            if (ov > rv || (ov == rv && oi < ridx)) { rv = ov; ridx = oi; rl = ol; }
        }
        if (k == 0) lmax = rv;
        if (t == 0) { w8s[k] = __expf(rv - lmax); s8s[k] = rl; }
        if (t == rl) myv = -1e30f;
    }
    __syncthreads();
    float cvv[8];
    float sq = 0.f;
    int idx = 0;
    for (int d = t; d < DDIM; d += 64, ++idx) {
        float s = 0.f;
        #pragma unroll
        for (int k = 0; k < KTOP; ++k)
            s = fmaf(w8s[k], ex_x[((size_t)p * NCAND + s8s[k]) * DDIM + d], s);
        cvv[idx] = s;
        sq += s * s;
    }
    #pragma unroll
    for (int s = 1; s < 64; s <<= 1) sq += __shfl_xor(sq, s);
    float norm = fmaxf(sqrtf(sq), 1e-12f);
    idx = 0;
    for (int d = t; d < DDIM; d += 64, ++idx)
        out[((size_t)b * NMEM + n) * DDIM + d] = cvv[idx] / norm;
}

extern "C" void kernel_launch(void* const* d_in, const int* in_sizes, int n_in,
                              void* d_out, int out_size, void* d_ws, size_t ws_size,
                              hipStream_t stream)
{
    const float* query = (const float*)d_in[0];
    const float* W1    = (const float*)d_in[1];
    const float* b1    = (const float*)d_in[2];
    const float* W2    = (const float*)d_in[3];
    const float* b2    = (const float*)d_in[4];
    const float* Wg    = (const float*)d_in[5];
    // d_in[6] = bg cancels under softmax+normalize; d_in[7] = topk (hardcoded 8)

    char* ws = (char*)d_ws;
    const size_t MB = 1024 * 1024;
    unsigned char* Q8   = (unsigned char*)(ws);                  // 8 MB
    unsigned char* W1T8 = (unsigned char*)(ws + 8 * MB);         // 4 MB
    unsigned char* W2T8 = (unsigned char*)(ws + 12 * MB);        // 4 MB
    float* logits   = (float*)(ws + 16 * MB);                    // 1 MB
    int*   cand     = (int*)  (ws + 17 * MB);                    // 8 KB
    float* ex_logit = (float*)(ws + 17 * MB + 16384);            // 8 KB
    float* ex_h     = (float*)(ws + 20 * MB);                    // 4 MB
    float* ex_x     = (float*)(ws + 28 * MB);                    // 4 MB

    prep_kernel<<<4352, 256, 0, stream>>>(query, W1, W2, Q8, W1T8, W2T8, logits);
    fused_mlp_kernel<<<4096, 256, 0, stream>>>(Q8, W1T8, W2T8, b1, b2, Wg, logits);
    topcand_kernel<<<64, 256, 0, stream>>>(logits, cand, ex_logit);
    exact_h_kernel<<<1024, 256, 0, stream>>>(query, W1, b1, cand, ex_h);
    exact_x_kernel<<<1024, 256, 0, stream>>>(ex_h, W2, b2, Wg, ex_x, ex_logit);
    final_kernel<<<64, 64, 0, stream>>>(ex_x, ex_logit, cand, (float*)d_out);
}

// Round 9
// 493.376 us; speedup vs baseline: 1.1971x; 1.1971x over previous
//
#include <hip/hip_runtime.h>
#include <hip/hip_bf16.h>
#include <cstdint>
#include <cstddef>

// Problem constants
#define NMEM 16
#define DDIM 512
#define BATCH 4
#define LSEQ 4096
#define ROWS 16384      // BATCH*LSEQ
#define NCAND 32        // fp8-noise safety: rank-8..32 gap ~4.5+ sigma
#define KTOP 8
#define QPAD 20

typedef __attribute__((ext_vector_type(4))) float f32x4;
typedef __attribute__((ext_vector_type(16))) float f32x16;
typedef __attribute__((ext_vector_type(8))) int int8v;

__device__ inline void gld16(const void* gptr, void* lptr) {
    __builtin_amdgcn_global_load_lds(
        (const __attribute__((address_space(1))) unsigned int*)gptr,
        (__attribute__((address_space(3))) unsigned int*)lptr,
        16, 0, 0);
}

__device__ inline float fast_tanh(float p) {
    p = fminf(fmaxf(p, -15.f), 15.f);
    float e = __expf(2.f * p);
    return (e - 1.f) / (e + 1.f);
}

// MX frag from a 128-B-row tile: chunks 2g^h, (2g+1)^h of row (h = swizzle key)
__device__ inline int8v load_frag(const unsigned char* Ts, int row, int g, int hs) {
    int h = (row >> hs) & 7;
    const int4* p0 = (const int4*)(Ts + row * 128 + (((2 * g) ^ h) << 4));
    const int4* p1 = (const int4*)(Ts + row * 128 + (((2 * g + 1) ^ h) << 4));
    int4 x = *p0, y = *p1;
    int8v v;
    v[0] = x.x; v[1] = x.y; v[2] = x.z; v[3] = x.w;
    v[4] = y.x; v[5] = y.y; v[6] = y.z; v[7] = y.w;
    return v;
}

// ---------- fused prep: Q->fp8, W1/W2 transpose->fp8, zero logits ----------
__global__ __launch_bounds__(256)
void prep_kernel(const float* __restrict__ query,
                 const float* __restrict__ W1, const float* __restrict__ W2,
                 unsigned char* __restrict__ Q8,
                 unsigned char* __restrict__ W1T8, unsigned char* __restrict__ W2T8,
                 float* __restrict__ logits) {
    int blk = blockIdx.x, t = threadIdx.x;
    if (blk < 2048) {                       // Q convert: 16 els/thread
        size_t base = ((size_t)blk * 256 + t) * 16;
        const float4* in = (const float4*)(query + base);
        int4 o; int* op = (int*)&o;
        #pragma unroll
        for (int q = 0; q < 4; ++q) {
            float4 v = in[q];
            int lo = __builtin_amdgcn_cvt_pk_fp8_f32(v.x, v.y, 0, false);
            op[q] = __builtin_amdgcn_cvt_pk_fp8_f32(v.z, v.w, lo, true);
        }
        *(int4*)(Q8 + base) = o;
    } else if (blk < 4096) {                // W transpose+convert, 64x64 tiles
        __shared__ float tile[64][69];
        int bid = blk - 2048;
        const float* Win = W1; unsigned char* Wout = W1T8;
        if (bid >= 1024) { bid -= 1024; Win = W2; Wout = W2T8; }
        int n = bid >> 6, t64 = bid & 63;
        int dt = (t64 >> 3) << 6, jt = (t64 & 7) << 6;
        const float* inN = Win + (size_t)n * DDIM * DDIM;
        unsigned char* outN = Wout + (size_t)n * DDIM * DDIM;
        int rr = t >> 4, cc = (t & 15) * 4;
        #pragma unroll
        for (int pass = 0; pass < 4; ++pass) {
            int row = rr + pass * 16;
            float4 v = *(const float4*)(inN + (size_t)(dt + row) * DDIM + jt + cc);
            tile[row][cc] = v.x; tile[row][cc + 1] = v.y;
            tile[row][cc + 2] = v.z; tile[row][cc + 3] = v.w;
        }
        __syncthreads();
        #pragma unroll
        for (int pass = 0; pass < 4; ++pass) {
            int jl = rr + pass * 16;
            float f0 = tile[cc][jl], f1 = tile[cc + 1][jl];
            float f2 = tile[cc + 2][jl], f3 = tile[cc + 3][jl];
            int lo = __builtin_amdgcn_cvt_pk_fp8_f32(f0, f1, 0, false);
            int dw = __builtin_amdgcn_cvt_pk_fp8_f32(f2, f3, lo, true);
            *(int*)(outN + (size_t)(jt + jl) * DDIM + dt + cc) = dw;
        }
    } else {                                // zero logits (1 MB)
        int bid = blk - 4096;
        ((int4*)logits)[bid * 256 + t] = int4{0, 0, 0, 0};
    }
}

// ---------- fused MLP (R7-best): M=128 rows/block, simple 2-barrier K-loop ----------
// grid 2048 = 128 m-tiles x 16 slots. Block 256 = 4 waves (rh, ch); wave tile
// 64 rows x 64 cols per 128-col chunk, 2x2 of 32x32x64 MX MFMA. h LDS-resident.
__global__ __launch_bounds__(256, 2)
void fused_mlp_kernel(const unsigned char* __restrict__ Q8,
                      const unsigned char* __restrict__ W1T8,
                      const unsigned char* __restrict__ W2T8,
                      const float* __restrict__ b1, const float* __restrict__ b2,
                      const float* __restrict__ Wg,
                      float* __restrict__ logits)
{
    __shared__ unsigned char hbuf[128 * 512];  // 64 KB fp8 h, chunk^row&7 swizzle
    __shared__ unsigned char Bs[128 * 128];    // 16 KB W-tile
    const int id = blockIdx.x;
    const int n = id & 15;
    const int m0 = (id >> 4) * 128;
    const int tid = threadIdx.x, lane = tid & 63, w = tid >> 6;
    const int rh = w >> 1, ch = w & 1;
    const int l31 = lane & 31, kh = lane >> 5;
    const unsigned char* W1n = W1T8 + (size_t)n * DDIM * DDIM;
    const unsigned char* W2n = W2T8 + (size_t)n * DDIM * DDIM;
    const float slope = 0.01f + 0.0125f * n;
    const unsigned char* Aq0 = Q8 + (size_t)(m0 + rh * 64 + l31) * DDIM + kh * 32;

    // ---- Phase A: h = leaky(Q W1 + b1) -> hbuf ----
    for (int n0 = 0; n0 < 4; ++n0) {
        f32x16 acc[2][2] = {};   // [rt][fc]
        const unsigned char* Bg = W1n + (size_t)(n0 * 128) * DDIM;
        for (int kt = 0; kt < 4; ++kt) {
            int8v av[2][2];      // [rt][ks]
            #pragma unroll
            for (int rt = 0; rt < 2; ++rt)
                #pragma unroll
                for (int ks = 0; ks < 2; ++ks) {
                    const unsigned char* ap = Aq0 + (size_t)rt * 32 * DDIM + kt * 128 + ks * 64;
                    int4 x = *(const int4*)ap;
                    int4 y = *(const int4*)(ap + 16);
                    av[rt][ks][0] = x.x; av[rt][ks][1] = x.y;
                    av[rt][ks][2] = x.z; av[rt][ks][3] = x.w;
                    av[rt][ks][4] = y.x; av[rt][ks][5] = y.y;
                    av[rt][ks][6] = y.z; av[rt][ks][7] = y.w;
                }
            #pragma unroll
            for (int i = 0; i < 4; ++i) {
                int c = i * 256 + tid;
                int row = c >> 3, chk = c & 7;
                gld16(Bg + (size_t)row * DDIM + kt * 128 + ((chk ^ (row & 7)) << 4),
                      &Bs[c * 16]);
            }
            __syncthreads();
            #pragma unroll
            for (int ks = 0; ks < 2; ++ks)
                #pragma unroll
                for (int fc = 0; fc < 2; ++fc) {
                    int8v bfr = load_frag(Bs, ch * 64 + fc * 32 + l31, ks * 2 + kh, 0);
                    #pragma unroll
                    for (int rt = 0; rt < 2; ++rt)
                        acc[rt][fc] = __builtin_amdgcn_mfma_scale_f32_32x32x64_f8f6f4(
                            av[rt][ks], bfr, acc[rt][fc], 0, 0, 0,
                            0x7F7F7F7F, 0, 0x7F7F7F7F);
                }
            __syncthreads();
        }
        #pragma unroll
        for (int fc = 0; fc < 2; ++fc) {
            int D = n0 * 128 + ch * 64 + fc * 32 + l31;
            float bias = b1[n * DDIM + D];
            #pragma unroll
            for (int rt = 0; rt < 2; ++rt)
                #pragma unroll
                for (int reg = 0; reg < 16; ++reg) {
                    int row = rh * 64 + rt * 32 + (reg & 3) + 8 * (reg >> 2) + 4 * kh;
                    float v = acc[rt][fc][reg] + bias;
                    v = v >= 0.f ? v : v * slope;
                    int pk = __builtin_amdgcn_cvt_pk_fp8_f32(v, v, 0, false);
                    hbuf[row * 512 + (((D >> 4) ^ (row & 7)) << 4) + (D & 15)]
                        = (unsigned char)(pk & 0xff);
                }
        }
    }

    // ---- Phase B: rowsum = sum_j tanh(h W2 + b2)[row][j] * Wg[j] ----
    float rowacc[2][16] = {};
    for (int n0 = 0; n0 < 4; ++n0) {
        f32x16 acc[2][2] = {};
        const unsigned char* Bg = W2n + (size_t)(n0 * 128) * DDIM;
        for (int kt = 0; kt < 4; ++kt) {
            #pragma unroll
            for (int i = 0; i < 4; ++i) {
                int c = i * 256 + tid;
                int row = c >> 3, chk = c & 7;
                gld16(Bg + (size_t)row * DDIM + kt * 128 + ((chk ^ (row & 7)) << 4),
                      &Bs[c * 16]);
            }
            __syncthreads();
            #pragma unroll
            for (int ks = 0; ks < 2; ++ks) {
                int8v av[2];
                #pragma unroll
                for (int rt = 0; rt < 2; ++rt) {
                    int hrow = rh * 64 + rt * 32 + l31, hq = hrow & 7;
                    int C0 = kt * 8 + ks * 4 + 2 * kh;
                    const int4* p0 = (const int4*)(hbuf + hrow * 512 + ((C0 ^ hq) << 4));
                    const int4* p1 = (const int4*)(hbuf + hrow * 512 + (((C0 + 1) ^ hq) << 4));
                    int4 x = *p0, y = *p1;
                    av[rt][0] = x.x; av[rt][1] = x.y; av[rt][2] = x.z; av[rt][3] = x.w;
                    av[rt][4] = y.x; av[rt][5] = y.y; av[rt][6] = y.z; av[rt][7] = y.w;
                }
                #pragma unroll
                for (int fc = 0; fc < 2; ++fc) {
                    int8v bfr = load_frag(Bs, ch * 64 + fc * 32 + l31, ks * 2 + kh, 0);
                    #pragma unroll
                    for (int rt = 0; rt < 2; ++rt)
                        acc[rt][fc] = __builtin_amdgcn_mfma_scale_f32_32x32x64_f8f6f4(
                            av[rt], bfr, acc[rt][fc], 0, 0, 0,
                            0x7F7F7F7F, 0, 0x7F7F7F7F);
                }
            }
            __syncthreads();
        }
        #pragma unroll
        for (int fc = 0; fc < 2; ++fc) {
            int j = n0 * 128 + ch * 64 + fc * 32 + l31;
            float bias = b2[n * DDIM + j];
            float wgv = Wg[n * DDIM + j];
            #pragma unroll
            for (int rt = 0; rt < 2; ++rt)
                #pragma unroll
                for (int reg = 0; reg < 16; ++reg)
                    rowacc[rt][reg] = fmaf(fast_tanh(acc[rt][fc][reg] + bias), wgv,
                                           rowacc[rt][reg]);
        }
    }
    #pragma unroll
    for (int sh = 1; sh < 32; sh <<= 1)
        #pragma unroll
        for (int rt = 0; rt < 2; ++rt)
            #pragma unroll
            for (int reg = 0; reg < 16; ++reg)
                rowacc[rt][reg] += __shfl_xor(rowacc[rt][reg], sh);
    if (l31 == 0) {
        float* Ln = logits + (size_t)n * ROWS + m0 + rh * 64 + 4 * kh;
        #pragma unroll
        for (int rt = 0; rt < 2; ++rt)
            #pragma unroll
            for (int reg = 0; reg < 16; ++reg)
                atomicAdd(&Ln[rt * 32 + (reg & 3) + 8 * (reg >> 2)], rowacc[rt][reg]);
    }
}

// ---------- topcand: per (n,b) top-32 of 4096 ----------
__global__ __launch_bounds__(256)
void topcand_kernel(const float* __restrict__ logits, int* __restrict__ cand,
                    float* __restrict__ ex_logit) {
    __shared__ float lv[LSEQ];
    __shared__ float cv[128];
    __shared__ int   ci[128];
    int p = blockIdx.x, n = p >> 2, b = p & 3;
    int t = threadIdx.x, lane = t & 63, w = t >> 6;
    const float* L = logits + (size_t)n * ROWS + (size_t)b * LSEQ;
    for (int i = t; i < LSEQ; i += 256) lv[i] = L[i];
    __syncthreads();
    float mv[16];
    int base = w * 1024;
    #pragma unroll
    for (int j = 0; j < 16; ++j) mv[j] = lv[base + j * 64 + lane];
    for (int rd = 0; rd < 32; ++rd) {
        float best = mv[0]; int bj = 0;
        #pragma unroll
        for (int j = 1; j < 16; ++j)
            if (mv[j] > best) { best = mv[j]; bj = j; }
        int bidx = base + bj * 64 + lane;
        float rv = best; int ridx = bidx;
        #pragma unroll
        for (int s = 1; s < 64; s <<= 1) {
            float ov = __shfl_xor(rv, s); int oi = __shfl_xor(ridx, s);
            if (ov > rv || (ov == rv && oi < ridx)) { rv = ov; ridx = oi; }
        }
        if (lane == 0) { cv[w * 32 + rd] = rv; ci[w * 32 + rd] = ridx; }
        if (ridx == bidx) mv[bj] = -1e30f;
    }
    __syncthreads();
    if (w == 0) {
        float v2[2]; int i2[2];
        #pragma unroll
        for (int k = 0; k < 2; ++k) { v2[k] = cv[k * 64 + lane]; i2[k] = ci[k * 64 + lane]; }
        for (int rd = 0; rd < 32; ++rd) {
            float best = v2[0]; int bi = i2[0]; int bk = 0;
            if (v2[1] > best || (v2[1] == best && i2[1] < bi)) { best = v2[1]; bi = i2[1]; bk = 1; }
            float rv = best; int ridx = bi;
            #pragma unroll
            for (int s = 1; s < 64; s <<= 1) {
                float ov = __shfl_xor(rv, s); int oi = __shfl_xor(ridx, s);
                if (ov > rv || (ov == rv && oi < ridx)) { rv = ov; ridx = oi; }
            }
            if (lane == 0) cand[p * NCAND + rd] = ridx;
            if (ridx == bi) v2[bk] = -1e30f;
        }
    } else if (w == 1) {
        if (lane < NCAND) ex_logit[p * NCAND + lane] = 0.f;
    }
}

// ---------- exact fp32 recompute v3: phase 1 (h) ----------
// grid 256 = 64 p x 4 jc; block handles 128 j-cols (jj, jj+64) x all 32 cands
// thread (jj 64, dg 4): 2 j-cols, 16 cands/pass, 32 fma per 4 ds_read_b128
__global__ __launch_bounds__(256)
void exact_h_kernel(const float* __restrict__ query,
                    const float* __restrict__ W1, const float* __restrict__ b1,
                    const int* __restrict__ cand, float* __restrict__ ex_h) {
    __shared__ float qs[DDIM][QPAD];        // 40 KB, 16 cands/pass
    __shared__ float hpart[4][16][64];      // 16 KB
    int blk = blockIdx.x;
    int p = blk >> 2, jc = blk & 3;
    int n = p >> 2, b = p & 3;
    int t = threadIdx.x, jj = t & 63, dg = t >> 6;
    int ja = jc * 128 + jj, jb = ja + 64;
    const float* W1n = W1 + (size_t)n * DDIM * DDIM;
    const float slope = 0.01f + 0.0125f * n;
    float ba = b1[n * DDIM + ja], bb2 = b1[n * DDIM + jb];

    for (int ct = 0; ct < 2; ++ct) {
        for (int c = 0; c < 16; ++c) {
            int li = cand[p * NCAND + ct * 16 + c];
            const float* qr = query + ((size_t)b * LSEQ + li) * DDIM;
            for (int d = t; d < DDIM; d += 256) qs[d][c] = qr[d];
        }
        __syncthreads();
        float acc[2][16] = {};
        for (int d = dg * 128; d < dg * 128 + 128; ++d) {
            float wa = W1n[(size_t)d * DDIM + ja];
            float wb = W1n[(size_t)d * DDIM + jb];
            const float4* qv = (const float4*)&qs[d][0];
            #pragma unroll
            for (int c4 = 0; c4 < 4; ++c4) {
                float4 q4 = qv[c4];
                acc[0][c4 * 4 + 0] = fmaf(q4.x, wa, acc[0][c4 * 4 + 0]);
                acc[0][c4 * 4 + 1] = fmaf(q4.y, wa, acc[0][c4 * 4 + 1]);
                acc[0][c4 * 4 + 2] = fmaf(q4.z, wa, acc[0][c4 * 4 + 2]);
                acc[0][c4 * 4 + 3] = fmaf(q4.w, wa, acc[0][c4 * 4 + 3]);
                acc[1][c4 * 4 + 0] = fmaf(q4.x, wb, acc[1][c4 * 4 + 0]);
                acc[1][c4 * 4 + 1] = fmaf(q4.y, wb, acc[1][c4 * 4 + 1]);
                acc[1][c4 * 4 + 2] = fmaf(q4.z, wb, acc[1][c4 * 4 + 2]);
                acc[1][c4 * 4 + 3] = fmaf(q4.w, wb, acc[1][c4 * 4 + 3]);
            }
        }
        #pragma unroll
        for (int half = 0; half < 2; ++half) {
            __syncthreads();
            #pragma unroll
            for (int c = 0; c < 16; ++c) hpart[dg][c][jj] = acc[half][c];
            __syncthreads();
            int j = half ? jb : ja;
            float bias = half ? bb2 : ba;
            for (int cc = dg; cc < 16; cc += 4) {
                float h = hpart[0][cc][jj] + hpart[1][cc][jj] + hpart[2][cc][jj]
                        + hpart[3][cc][jj] + bias;
                h = h >= 0.f ? h : h * slope;
                ex_h[((size_t)p * NCAND + ct * 16 + cc) * DDIM + j] = h;
            }
        }
        __syncthreads();   // before re-staging qs
    }
}

// ---------- exact v3 phase 2: x + exact logits ----------
__global__ __launch_bounds__(256)
void exact_x_kernel(const float* __restrict__ ex_h,
                    const float* __restrict__ W2, const float* __restrict__ b2,
                    const float* __restrict__ Wg,
                    float* __restrict__ ex_x, float* __restrict__ ex_logit) {
    __shared__ float hs[DDIM][QPAD];
    __shared__ float xpart[4][16][64];
    int blk = blockIdx.x;
    int p = blk >> 2, jc = blk & 3;
    int n = p >> 2;
    int t = threadIdx.x, jj = t & 63, dg = t >> 6;
    int ja = jc * 128 + jj, jb = ja + 64;
    const float* W2n = W2 + (size_t)n * DDIM * DDIM;
    float b2a = b2[n * DDIM + ja], b2b = b2[n * DDIM + jb];
    float wga = Wg[n * DDIM + ja], wgb = Wg[n * DDIM + jb];

    for (int ct = 0; ct < 2; ++ct) {
        for (int c = 0; c < 16; ++c) {
            const float* hr = ex_h + ((size_t)p * NCAND + ct * 16 + c) * DDIM;
            for (int d = t; d < DDIM; d += 256) hs[d][c] = hr[d];
        }
        __syncthreads();
        float acc[2][16] = {};
        for (int d = dg * 128; d < dg * 128 + 128; ++d) {
            float wa = W2n[(size_t)d * DDIM + ja];
            float wb = W2n[(size_t)d * DDIM + jb];
            const float4* hv = (const float4*)&hs[d][0];
            #pragma unroll
            for (int c4 = 0; c4 < 4; ++c4) {
                float4 h4 = hv[c4];
                acc[0][c4 * 4 + 0] = fmaf(h4.x, wa, acc[0][c4 * 4 + 0]);
                acc[0][c4 * 4 + 1] = fmaf(h4.y, wa, acc[0][c4 * 4 + 1]);
                acc[0][c4 * 4 + 2] = fmaf(h4.z, wa, acc[0][c4 * 4 + 2]);
                acc[0][c4 * 4 + 3] = fmaf(h4.w, wa, acc[0][c4 * 4 + 3]);
                acc[1][c4 * 4 + 0] = fmaf(h4.x, wb, acc[1][c4 * 4 + 0]);
                acc[1][c4 * 4 + 1] = fmaf(h4.y, wb, acc[1][c4 * 4 + 1]);
                acc[1][c4 * 4 + 2] = fmaf(h4.z, wb, acc[1][c4 * 4 + 2]);
                acc[1][c4 * 4 + 3] = fmaf(h4.w, wb, acc[1][c4 * 4 + 3]);
            }
        }
        #pragma unroll
        for (int half = 0; half < 2; ++half) {
            __syncthreads();
            #pragma unroll
            for (int c = 0; c < 16; ++c) xpart[dg][c][jj] = acc[half][c];
            __syncthreads();
            int j = half ? jb : ja;
            float bias = half ? b2b : b2a;
            float wg = half ? wgb : wga;
            for (int cc = dg; cc < 16; cc += 4) {
                float a = xpart[0][cc][jj] + xpart[1][cc][jj] + xpart[2][cc][jj]
                        + xpart[3][cc][jj] + bias;
                float x = tanhf(a);
                ex_x[((size_t)p * NCAND + ct * 16 + cc) * DDIM + j] = x;
                float lp = x * wg;
                #pragma unroll
                for (int s = 1; s < 64; s <<= 1) lp += __shfl_xor(lp, s);
                if (jj == 0) atomicAdd(&ex_logit[p * NCAND + ct * 16 + cc], lp);
            }
        }
        __syncthreads();
    }
}

// ---------- final: exact top-8 of 32, weight, combine, normalize ----------
__global__ __launch_bounds__(64)
void final_kernel(const float* __restrict__ ex_x, const float* __restrict__ ex_logit,
                  const int* __restrict__ cand, float* __restrict__ out)
{
    __shared__ float w8s[KTOP];
    __shared__ int   s8s[KTOP];
    int p = blockIdx.x, n = p >> 2, b = p & 3;
    int t = threadIdx.x;
    float myv = (t < NCAND) ? ex_logit[p * NCAND + t] : -1e30f;
    int myidx = (t < NCAND) ? cand[p * NCAND + t] : 0x7fffffff;
    float lmax = 0.f;
    for (int k = 0; k < KTOP; ++k) {
        float rv = myv; int ridx = myidx; int rl = t;
        #pragma unroll
        for (int s = 1; s < 64; s <<= 1) {
            float ov = __shfl_xor(rv, s); int oi = __shfl_xor(ridx, s); int ol = __shfl_xor(rl, s);
            if (ov > rv || (ov == rv && oi < ridx)) { rv = ov; ridx = oi; rl = ol; }
        }
        if (k == 0) lmax = rv;
        if (t == 0) { w8s[k] = __expf(rv - lmax); s8s[k] = rl; }
        if (t == rl) myv = -1e30f;
    }
    __syncthreads();
    float cvv[8];
    float sq = 0.f;
    int idx = 0;
    for (int d = t; d < DDIM; d += 64, ++idx) {
        float s = 0.f;
        #pragma unroll
        for (int k = 0; k < KTOP; ++k)
            s = fmaf(w8s[k], ex_x[((size_t)p * NCAND + s8s[k]) * DDIM + d], s);
        cvv[idx] = s;
        sq += s * s;
    }
    #pragma unroll
    for (int s = 1; s < 64; s <<= 1) sq += __shfl_xor(sq, s);
    float norm = fmaxf(sqrtf(sq), 1e-12f);
    idx = 0;
    for (int d = t; d < DDIM; d += 64, ++idx)
        out[((size_t)b * NMEM + n) * DDIM + d] = cvv[idx] / norm;
}

extern "C" void kernel_launch(void* const* d_in, const int* in_sizes, int n_in,
                              void* d_out, int out_size, void* d_ws, size_t ws_size,
                              hipStream_t stream)
{
    const float* query = (const float*)d_in[0];
    const float* W1    = (const float*)d_in[1];
    const float* b1    = (const float*)d_in[2];
    const float* W2    = (const float*)d_in[3];
    const float* b2    = (const float*)d_in[4];
    const float* Wg    = (const float*)d_in[5];
    // d_in[6] = bg cancels under softmax+normalize; d_in[7] = topk (hardcoded 8)

    char* ws = (char*)d_ws;
    const size_t MB = 1024 * 1024;
    unsigned char* Q8   = (unsigned char*)(ws);                  // 8 MB
    unsigned char* W1T8 = (unsigned char*)(ws + 8 * MB);         // 4 MB
    unsigned char* W2T8 = (unsigned char*)(ws + 12 * MB);        // 4 MB
    float* logits   = (float*)(ws + 16 * MB);                    // 1 MB
    int*   cand     = (int*)  (ws + 17 * MB);                    // 8 KB
    float* ex_logit = (float*)(ws + 17 * MB + 16384);            // 8 KB
    float* ex_h     = (float*)(ws + 20 * MB);                    // 4 MB
    float* ex_x     = (float*)(ws + 28 * MB);                    // 4 MB

    prep_kernel<<<4352, 256, 0, stream>>>(query, W1, W2, Q8, W1T8, W2T8, logits);
    fused_mlp_kernel<<<2048, 256, 0, stream>>>(Q8, W1T8, W2T8, b1, b2, Wg, logits);
    topcand_kernel<<<64, 256, 0, stream>>>(logits, cand, ex_logit);
    exact_h_kernel<<<256, 256, 0, stream>>>(query, W1, b1, cand, ex_h);
    exact_x_kernel<<<256, 256, 0, stream>>>(ex_h, W2, b2, Wg, ex_x, ex_logit);
    final_kernel<<<64, 64, 0, stream>>>(ex_x, ex_logit, cand, (float*)d_out);
}